// Round 8
// baseline (48.164 us; speedup 1.0000x reference)
//
#include <hip/hip_runtime.h>
#include <math.h>

#define SEQ_L 4096
#define LDS_PAD 260          // covers prefetch over-read past the last iteration

// 6-step gfx9 DPP wave64 sum; result valid in lane 63. (verified R5)
__device__ __forceinline__ float wave_sum_dpp(float x) {
    int t;
    t = __builtin_amdgcn_update_dpp(0, __float_as_int(x), 0x111, 0xf, 0xf, true); x += __int_as_float(t);
    t = __builtin_amdgcn_update_dpp(0, __float_as_int(x), 0x112, 0xf, 0xf, true); x += __int_as_float(t);
    t = __builtin_amdgcn_update_dpp(0, __float_as_int(x), 0x114, 0xf, 0xf, true); x += __int_as_float(t);
    t = __builtin_amdgcn_update_dpp(0, __float_as_int(x), 0x118, 0xf, 0xf, true); x += __int_as_float(t);
    t = __builtin_amdgcn_update_dpp(0, __float_as_int(x), 0x142, 0xa, 0xf, true); x += __int_as_float(t);
    t = __builtin_amdgcn_update_dpp(0, __float_as_int(x), 0x143, 0xc, 0xf, true); x += __int_as_float(t);
    return x;
}

// One group of 4 rows {b0, b0+19, b0+38, b0+57} sharing a mod-19 cos class.
__device__ __forceinline__ void do_group(
    int b0, int lane, const float2* __restrict__ x2,
    const float* As, const float* Ws, float2* __restrict__ outp,
    float scaleL2, float cphi, float sphi,
    float cd, float sd, float ck1, float sk1, float ck2, float sk2,
    float ck3, float sk3, float ga, float gc, float cw)
{
    const float LOG2E = 1.4426950408889634f;
    const float SQRT2 = 1.4142135623730951f;
    const int i0 = b0, i1 = b0 + 19, i2 = b0 + 38, i3 = b0 + 57;
    const int c1 = i1 < SEQ_L ? i1 : SEQ_L - 1;
    const int c2 = i2 < SEQ_L ? i2 : SEQ_L - 1;
    const int c3 = i3 < SEQ_L ? i3 : SEQ_L - 1;

    const float t20 = scaleL2 * As[i0], t21 = scaleL2 * As[c1];
    const float t22 = scaleL2 * As[c2], t23 = scaleL2 * As[c3];
    const float M20 = fabsf(t20) * SQRT2, M21 = fabsf(t21) * SQRT2;
    const float M22 = fabsf(t22) * SQRT2, M23 = fabsf(t23) * SQRT2;

    const float2 xv0 = x2[i0], xv1 = x2[c1], xv2 = x2[c2], xv3 = x2[c3];

    unsigned r = (unsigned)(b0 - (lane << 2) + 266) % 19u;   // 266 = 14*19
    float rev = (float)r * (1.0f / 19.0f);
    float crv = __builtin_amdgcn_cosf(rev);
    float srv = __builtin_amdgcn_sinf(rev);
    float C = fmaf(srv, sphi, crv * cphi);
    float S = fmaf(crv, -sphi, srv * cphi);

    float sa0=0.f, sa1=0.f, sa2=0.f, sa3=0.f;
    float oa0=0.f, oa1=0.f, oa2=0.f, oa3=0.f;
    int jb = lane << 2;
    const int ncom = (b0 + 1) >> 8;
    const int T    = (c3 >> 8) + 1;

#define EL4(u, pw) { \
    float e0_ = __builtin_amdgcn_exp2f(fmaf(t20, (u), -M20)); \
    float e1_ = __builtin_amdgcn_exp2f(fmaf(t21, (u), -M21)); \
    float e2_ = __builtin_amdgcn_exp2f(fmaf(t22, (u), -M22)); \
    float e3_ = __builtin_amdgcn_exp2f(fmaf(t23, (u), -M23)); \
    sa0 += e0_; oa0 = fmaf(e0_, (pw), oa0); \
    sa1 += e1_; oa1 = fmaf(e1_, (pw), oa1); \
    sa2 += e2_; oa2 = fmaf(e2_, (pw), oa2); \
    sa3 += e3_; oa3 = fmaf(e3_, (pw), oa3); }
#define ELM4(u, pw, jj) { \
    float e0_ = __builtin_amdgcn_exp2f(fmaf(t20, (u), -M20)); \
    float e1_ = __builtin_amdgcn_exp2f(fmaf(t21, (u), -M21)); \
    float e2_ = __builtin_amdgcn_exp2f(fmaf(t22, (u), -M22)); \
    float e3_ = __builtin_amdgcn_exp2f(fmaf(t23, (u), -M23)); \
    e0_ = ((jj) <= i0) ? e0_ : 0.f; \
    e1_ = ((jj) <= i1) ? e1_ : 0.f; \
    e2_ = ((jj) <= i2) ? e2_ : 0.f; \
    e3_ = ((jj) <= i3) ? e3_ : 0.f; \
    sa0 += e0_; oa0 = fmaf(e0_, (pw), oa0); \
    sa1 += e1_; oa1 = fmaf(e1_, (pw), oa1); \
    sa2 += e2_; oa2 = fmaf(e2_, (pw), oa2); \
    sa3 += e3_; oa3 = fmaf(e3_, (pw), oa3); }
#define ROT() { \
    float Cn_ = fmaf(S, sd, C * cd); \
    float Sn_ = fmaf(S, cd, -(C * sd)); \
    C = Cn_; S = Sn_; }

    float4 av = *(const float4*)&As[jb];
    float4 wv = *(const float4*)&Ws[jb];
    int t = 0;
    for (; t < ncom; ++t) {
        float4 avn = *(const float4*)&As[jb + 256];
        float4 wvn = *(const float4*)&Ws[jb + 256];
        float C1 = fmaf(S, sk1, C * ck1);
        float C2 = fmaf(S, sk2, C * ck2);
        float C3 = fmaf(S, sk3, C * ck3);
        float u0 = av.x * C,  u1 = av.y * C1;
        float u2 = av.z * C2, u3 = av.w * C3;
        EL4(u0, wv.x) EL4(u1, wv.y) EL4(u2, wv.z) EL4(u3, wv.w)
        ROT();
        av = avn; wv = wvn; jb += 256;
    }
    for (; t < T; ++t) {
        float4 avn = *(const float4*)&As[jb + 256];
        float4 wvn = *(const float4*)&Ws[jb + 256];
        float C1 = fmaf(S, sk1, C * ck1);
        float C2 = fmaf(S, sk2, C * ck2);
        float C3 = fmaf(S, sk3, C * ck3);
        float u0 = av.x * C,  u1 = av.y * C1;
        float u2 = av.z * C2, u3 = av.w * C3;
        ELM4(u0, wv.x, jb)     ELM4(u1, wv.y, jb + 1)
        ELM4(u2, wv.z, jb + 2) ELM4(u3, wv.w, jb + 3)
        ROT();
        av = avn; wv = wvn; jb += 256;
    }
#undef EL4
#undef ELM4
#undef ROT

    float S0 = wave_sum_dpp(sa0), O0 = wave_sum_dpp(oa0);
    float S1 = wave_sum_dpp(sa1), O1 = wave_sum_dpp(oa1);
    float S2 = wave_sum_dpp(sa2), O2 = wave_sum_dpp(oa2);
    float S3 = wave_sum_dpp(sa3), O3 = wave_sum_dpp(oa3);

    if (lane == 63) {
#define EPI(Sk, Ok, ik, xvk) if ((ik) < SEQ_L) { \
    float o0_ = (Ok) * __builtin_amdgcn_rcpf(Sk); \
    float h0_ = (xvk).x, h1_ = (xvk).y + o0_; \
    float inv_ = __builtin_amdgcn_rsqf(fmaf(h0_, h0_*0.5f, fmaf(h1_, h1_*0.5f, 1e-6f))); \
    float hn0_ = h0_ * inv_, hn1_ = h1_ * inv_; \
    float g0_ = hn0_ * ga + hn1_ * gc; \
    float g1_ = hn0_ * (ga - gc * 1e-3f) + hn1_ * gc; \
    float sg0_ = __builtin_amdgcn_rcpf(1.f + __builtin_amdgcn_exp2f(-g0_ * LOG2E)); \
    float sg1_ = __builtin_amdgcn_rcpf(1.f + __builtin_amdgcn_exp2f(-g1_ * LOG2E)); \
    float y1_ = cw * (g1_ * sg1_ - g0_ * sg0_) * hn0_; \
    outp[ik] = make_float2(h0_, h1_ + y1_); }
        EPI(S0, O0, i0, xv0)
        EPI(S1, O1, i1, xv1)
        EPI(S2, O2, i2, xv2)
        EPI(S3, O3, i3, xv3)
#undef EPI
    }
}

__global__ __launch_bounds__(256, 4) void attn_rows_kernel(
    const float* __restrict__ x,
    const float* __restrict__ q_weight,
    const float* __restrict__ v_weight,
    const float* __restrict__ gate_weight,
    const float* __restrict__ carry_weight,
    float* __restrict__ out,
    float scaleL2,
    float cd, float sd,
    float ck1, float sk1, float ck2, float sk2, float ck3, float sk3)
{
    __shared__ float As[SEQ_L + LDS_PAD];
    __shared__ float Ws[SEQ_L + LDS_PAD];

    const int tid  = threadIdx.x;
    const int lane = tid & 63;
    const int wave = tid >> 6;
    const int bat  = blockIdx.x / 129;
    const int bb   = blockIdx.x % 129;

    const float phi = q_weight[0];
    const float vw  = v_weight[0];
    const float2* x2 = (const float2*)x + (size_t)bat * SEQ_L;
    float2* outp = (float2*)out + (size_t)bat * SEQ_L;

    const float INV2PI = 0.15915494309189535f;
    const float rphi = phi * INV2PI;
    const float cphi = __builtin_amdgcn_cosf(rphi);
    const float sphi = __builtin_amdgcn_sinf(rphi);

    const float4* x4 = (const float4*)x2;
    #pragma unroll
    for (int it = 0; it < 8; ++it) {
        int idx = tid + (it << 8);
        float4 v = x4[idx];
        int e0 = idx << 1, e1 = e0 + 1;
        float inv0 = __builtin_amdgcn_rsqf(fmaf(v.x, v.x*0.5f, fmaf(v.y, v.y*0.5f, 1e-6f)));
        float xn0a = v.x * inv0;
        As[e0] = xn0a * __builtin_amdgcn_rsqf(fmaf(xn0a, xn0a*0.5f, 1e-6f));
        Ws[e0] = v.y * inv0 * vw;
        float inv1 = __builtin_amdgcn_rsqf(fmaf(v.z, v.z*0.5f, fmaf(v.w, v.w*0.5f, 1e-6f)));
        float xn0b = v.z * inv1;
        As[e1] = xn0b * __builtin_amdgcn_rsqf(fmaf(xn0b, xn0b*0.5f, 1e-6f));
        Ws[e1] = v.w * inv1 * vw;
    }
    __syncthreads();

    const int p = bb * 4 + wave;
    if (p >= 513) return;

    const float ga = gate_weight[0];
    const float gc = gate_weight[1];
    const float cw = carry_weight[0];

    const int m = p / 19;
    const int c = p - 19 * m;
    const int b0A = 76 * m + c;              // light group (b0 <= 1994)
    const int b0B = 4046 - b0A;              // mirror heavy group (>= 2052)

    // R8 DIAGNOSTIC: repeat the post-staging work 4x (idempotent — each rep
    // recomputes and rewrites identical outputs). Purpose: (a) push this
    // kernel's dispatch above the 40us fillBuffer dispatches so its rocprof
    // counters appear in top-5; (b) decompose K = staging + loop via
    // dur ~= F + staging + 4*(loop+epilogue). Memory clobber pins the loop.
    for (int rep = 0; rep < 4; ++rep) {
        asm volatile("" ::: "memory");
        do_group(b0A, lane, x2, As, Ws, outp, scaleL2, cphi, sphi,
                 cd, sd, ck1, sk1, ck2, sk2, ck3, sk3, ga, gc, cw);
        do_group(b0B, lane, x2, As, Ws, outp, scaleL2, cphi, sphi,
                 cd, sd, ck1, sk1, ck2, sk2, ck3, sk3, ga, gc, cw);
    }
}

extern "C" void kernel_launch(void* const* d_in, const int* in_sizes, int n_in,
                              void* d_out, int out_size, void* d_ws, size_t ws_size,
                              hipStream_t stream)
{
    const float* x  = (const float*)d_in[0];
    // d_in[1] = mask — causality handled analytically, unused
    const float* qw = (const float*)d_in[2];
    const float* vw = (const float*)d_in[3];
    const float* gw = (const float*)d_in[4];
    const float* cw = (const float*)d_in[5];
    float* out = (float*)d_out;

    const double omega = 2.0 * M_PI / 19.0;
    const double amp   = log(10.0) / (cos(omega * 0.3) - cos(omega * 0.7));
    const double qkns2 = amp / sqrt(2.0);               // QK_NORM_SCALE^2
    const double scale = pow(2.0, -0.5) * qkns2;        // HEAD_DIM^-0.5 * QK_NORM_SCALE^2
    const double L2E   = 1.4426950408889634074;
    const double delta = 256.0 * omega;                 // per-iteration angle decrement

    attn_rows_kernel<<<dim3(4 * 129), dim3(256), 0, stream>>>(
        x, qw, vw, gw, cw, out,
        (float)(scale * L2E),
        (float)cos(delta),       (float)sin(delta),
        (float)cos(omega),       (float)sin(omega),
        (float)cos(2.0 * omega), (float)sin(2.0 * omega),
        (float)cos(3.0 * omega), (float)sin(3.0 * omega));
}

// Round 9
// 17.544 us; speedup vs baseline: 2.7453x; 2.7453x over previous
//
#include <hip/hip_runtime.h>
#include <math.h>

#define SEQ_L 4096
#define LDS_PAD 260

// 6-step gfx9 DPP wave64 sum; result valid in lane 63. (verified R5-R8)
__device__ __forceinline__ float wave_sum_dpp(float x) {
    int t;
    t = __builtin_amdgcn_update_dpp(0, __float_as_int(x), 0x111, 0xf, 0xf, true); x += __int_as_float(t);
    t = __builtin_amdgcn_update_dpp(0, __float_as_int(x), 0x112, 0xf, 0xf, true); x += __int_as_float(t);
    t = __builtin_amdgcn_update_dpp(0, __float_as_int(x), 0x114, 0xf, 0xf, true); x += __int_as_float(t);
    t = __builtin_amdgcn_update_dpp(0, __float_as_int(x), 0x118, 0xf, 0xf, true); x += __int_as_float(t);
    t = __builtin_amdgcn_update_dpp(0, __float_as_int(x), 0x142, 0xa, 0xf, true); x += __int_as_float(t);
    t = __builtin_amdgcn_update_dpp(0, __float_as_int(x), 0x143, 0xc, 0xf, true); x += __int_as_float(t);
    return x;
}

// Schraudolph-style 2^x on log2-domain arg (already includes -M2, so x<=0):
// bits = (x + 126.9569)*2^23, clamped below at 1*2^23 (x<=-125.96 -> ~2^-126).
// Max relative error +-3.0%.
#define FEXP2(dst, t2s, u, Bs) { \
    float bf_ = fmaf((t2s), (u), (Bs)); \
    bf_ = fmaxf(bf_, 8388608.0f); \
    dst = __int_as_float((int)bf_); }

// Process one group of 4 rows {b0,b0+19,b0+38,b0+57}; this wave does
// iterations t = h, h+2, ... (parity split across 2 waves per pair).
// Writes 8 partial floats (s,o per row) to Pout[0..7].
__device__ __forceinline__ void do_group_half(
    int b0, int lane, int h,
    const float* As, const float* Ws, float* Pout,
    float scaleL2, float cphi, float sphi,
    float cd, float sd, float cd2, float sd2,
    float ck1, float sk1, float ck2, float sk2, float ck3, float sk3)
{
    const float SQRT2 = 1.4142135623730951f;
    const float EXPSC = 8388608.0f;          // 2^23
    const float EXPB  = 126.956945f;         // 127 - 0.043055 (centered)
    const int i0 = b0, i1 = b0 + 19, i2 = b0 + 38, i3 = b0 + 57;
    const int c1 = i1 < SEQ_L ? i1 : SEQ_L - 1;
    const int c2 = i2 < SEQ_L ? i2 : SEQ_L - 1;
    const int c3 = i3 < SEQ_L ? i3 : SEQ_L - 1;

    const float t20 = scaleL2 * As[i0], t21 = scaleL2 * As[c1];
    const float t22 = scaleL2 * As[c2], t23 = scaleL2 * As[c3];
    // scaled fma coefficients for the bit-trick exp
    const float t2s0 = t20 * EXPSC, t2s1 = t21 * EXPSC;
    const float t2s2 = t22 * EXPSC, t2s3 = t23 * EXPSC;
    const float Bs0 = (EXPB - fabsf(t20) * SQRT2) * EXPSC;
    const float Bs1 = (EXPB - fabsf(t21) * SQRT2) * EXPSC;
    const float Bs2 = (EXPB - fabsf(t22) * SQRT2) * EXPSC;
    const float Bs3 = (EXPB - fabsf(t23) * SQRT2) * EXPSC;

    // shared angle state: theta = omega*((b0 - 4*lane) mod 19) - phi
    unsigned r = (unsigned)(b0 - (lane << 2) + 266) % 19u;   // 266 = 14*19
    float rev = (float)r * (1.0f / 19.0f);
    float crv = __builtin_amdgcn_cosf(rev);
    float srv = __builtin_amdgcn_sinf(rev);
    float C = fmaf(srv, sphi, crv * cphi);
    float S = fmaf(crv, -sphi, srv * cphi);
    if (h) {                               // offset by one 256-step
        float Cn = fmaf(S, sd, C * cd);
        float Sn = fmaf(S, cd, -(C * sd));
        C = Cn; S = Sn;
    }

    float sa0=0.f, sa1=0.f, sa2=0.f, sa3=0.f;
    float oa0=0.f, oa1=0.f, oa2=0.f, oa3=0.f;
    int jb = (lane << 2) + (h << 8);
    const int ncom = (b0 + 1) >> 8;
    const int T    = (c3 >> 8) + 1;

#define EL4S(u, pw) { \
    float e0_, e1_, e2_, e3_; \
    FEXP2(e0_, t2s0, (u), Bs0) \
    FEXP2(e1_, t2s1, (u), Bs1) \
    FEXP2(e2_, t2s2, (u), Bs2) \
    FEXP2(e3_, t2s3, (u), Bs3) \
    sa0 += e0_; oa0 = fmaf(e0_, (pw), oa0); \
    sa1 += e1_; oa1 = fmaf(e1_, (pw), oa1); \
    sa2 += e2_; oa2 = fmaf(e2_, (pw), oa2); \
    sa3 += e3_; oa3 = fmaf(e3_, (pw), oa3); }
#define ELM4S(u, pw, jj) { \
    float e0_, e1_, e2_, e3_; \
    FEXP2(e0_, t2s0, (u), Bs0) \
    FEXP2(e1_, t2s1, (u), Bs1) \
    FEXP2(e2_, t2s2, (u), Bs2) \
    FEXP2(e3_, t2s3, (u), Bs3) \
    e0_ = ((jj) <= i0) ? e0_ : 0.f; \
    e1_ = ((jj) <= i1) ? e1_ : 0.f; \
    e2_ = ((jj) <= i2) ? e2_ : 0.f; \
    e3_ = ((jj) <= i3) ? e3_ : 0.f; \
    sa0 += e0_; oa0 = fmaf(e0_, (pw), oa0); \
    sa1 += e1_; oa1 = fmaf(e1_, (pw), oa1); \
    sa2 += e2_; oa2 = fmaf(e2_, (pw), oa2); \
    sa3 += e3_; oa3 = fmaf(e3_, (pw), oa3); }
#define ROT2() { \
    float Cn_ = fmaf(S, sd2, C * cd2); \
    float Sn_ = fmaf(S, cd2, -(C * sd2)); \
    C = Cn_; S = Sn_; }

    int t = h;
    for (; t < ncom; t += 2) {
        float4 av = *(const float4*)&As[jb];
        float4 wv = *(const float4*)&Ws[jb];
        float C1 = fmaf(S, sk1, C * ck1);
        float C2 = fmaf(S, sk2, C * ck2);
        float C3 = fmaf(S, sk3, C * ck3);
        float u0 = av.x * C,  u1 = av.y * C1;
        float u2 = av.z * C2, u3 = av.w * C3;
        EL4S(u0, wv.x) EL4S(u1, wv.y) EL4S(u2, wv.z) EL4S(u3, wv.w)
        ROT2();
        jb += 512;
    }
    for (; t < T; t += 2) {
        float4 av = *(const float4*)&As[jb];
        float4 wv = *(const float4*)&Ws[jb];
        float C1 = fmaf(S, sk1, C * ck1);
        float C2 = fmaf(S, sk2, C * ck2);
        float C3 = fmaf(S, sk3, C * ck3);
        float u0 = av.x * C,  u1 = av.y * C1;
        float u2 = av.z * C2, u3 = av.w * C3;
        ELM4S(u0, wv.x, jb)     ELM4S(u1, wv.y, jb + 1)
        ELM4S(u2, wv.z, jb + 2) ELM4S(u3, wv.w, jb + 3)
        ROT2();
        jb += 512;
    }
#undef EL4S
#undef ELM4S
#undef ROT2

    float S0 = wave_sum_dpp(sa0), O0 = wave_sum_dpp(oa0);
    float S1 = wave_sum_dpp(sa1), O1 = wave_sum_dpp(oa1);
    float S2 = wave_sum_dpp(sa2), O2 = wave_sum_dpp(oa2);
    float S3 = wave_sum_dpp(sa3), O3 = wave_sum_dpp(oa3);

    if (lane == 63) {
        Pout[0] = S0; Pout[1] = O0;
        Pout[2] = S1; Pout[3] = O1;
        Pout[4] = S2; Pout[5] = O2;
        Pout[6] = S3; Pout[7] = O3;
    }
}

__global__ __launch_bounds__(256, 4) void attn_rows_kernel(
    const float* __restrict__ x,
    const float* __restrict__ q_weight,
    const float* __restrict__ v_weight,
    const float* __restrict__ gate_weight,
    const float* __restrict__ carry_weight,
    float* __restrict__ out,
    float scaleL2,
    float cd, float sd,      // cos/sin(256*omega)
    float cd2, float sd2,    // cos/sin(512*omega)
    float ck1, float sk1, float ck2, float sk2, float ck3, float sk3)
{
    __shared__ float As[SEQ_L + LDS_PAD];
    __shared__ float Ws[SEQ_L + LDS_PAD];
    __shared__ float P[2][2][16];    // [pair_local][half][8 rows x (s,o)]

    const int tid  = threadIdx.x;
    const int lane = tid & 63;
    const int wave = tid >> 6;
    const int pl   = wave >> 1;      // pair within block: 0,1
    const int h    = wave & 1;       // parity half: 0,1
    const int bat  = blockIdx.x / 257;
    const int bb   = blockIdx.x % 257;

    const float phi = q_weight[0];
    const float vw  = v_weight[0];
    const float2* x2 = (const float2*)x + (size_t)bat * SEQ_L;
    float2* outp = (float2*)out + (size_t)bat * SEQ_L;

    const float INV2PI = 0.15915494309189535f;
    const float rphi = phi * INV2PI;
    const float cphi = __builtin_amdgcn_cosf(rphi);
    const float sphi = __builtin_amdgcn_sinf(rphi);

    const float4* x4 = (const float4*)x2;
    #pragma unroll
    for (int it = 0; it < 8; ++it) {
        int idx = tid + (it << 8);
        float4 v = x4[idx];
        int e0 = idx << 1, e1 = e0 + 1;
        float inv0 = __builtin_amdgcn_rsqf(fmaf(v.x, v.x*0.5f, fmaf(v.y, v.y*0.5f, 1e-6f)));
        float xn0a = v.x * inv0;
        As[e0] = xn0a * __builtin_amdgcn_rsqf(fmaf(xn0a, xn0a*0.5f, 1e-6f));
        Ws[e0] = v.y * inv0 * vw;
        float inv1 = __builtin_amdgcn_rsqf(fmaf(v.z, v.z*0.5f, fmaf(v.w, v.w*0.5f, 1e-6f)));
        float xn0b = v.z * inv1;
        As[e1] = xn0b * __builtin_amdgcn_rsqf(fmaf(xn0b, xn0b*0.5f, 1e-6f));
        Ws[e1] = v.w * inv1 * vw;
    }
    __syncthreads();

    const int p = bb * 2 + pl;           // pair index 0..512
    const bool active = (p < 513);
    int b0A = 0, b0B = 0;
    if (active) {
        const int m = p / 19;
        const int c = p - 19 * m;
        b0A = 76 * m + c;                // light group (<=1994)
        b0B = 4046 - b0A;                // mirror heavy group (>=2052)
        do_group_half(b0A, lane, h, As, Ws, &P[pl][h][0],
                      scaleL2, cphi, sphi, cd, sd, cd2, sd2,
                      ck1, sk1, ck2, sk2, ck3, sk3);
        do_group_half(b0B, lane, h, As, Ws, &P[pl][h][8],
                      scaleL2, cphi, sphi, cd, sd, cd2, sd2,
                      ck1, sk1, ck2, sk2, ck3, sk3);
    }
    __syncthreads();

    // combine halves + epilogue: wave h==0, 8 lanes = 8 rows of this pair
    if (active && h == 0 && lane < 8) {
        const float ga = gate_weight[0];
        const float gc = gate_weight[1];
        const float cw = carry_weight[0];
        const float LOG2E = 1.4426950408889634f;

        const int rsub = lane & 3;
        const int i = (lane < 4) ? (b0A + 19 * rsub) : (b0B + 19 * rsub);
        const int k = lane * 2;          // 0..15 within P[pl][.][16]
        if (i < SEQ_L) {
            float s = P[pl][0][k]     + P[pl][1][k];
            float o = P[pl][0][k + 1] + P[pl][1][k + 1];
            float o0 = o * __builtin_amdgcn_rcpf(s);
            float2 xv = x2[i];
            float h0 = xv.x, h1 = xv.y + o0;
            float inv = __builtin_amdgcn_rsqf(
                           fmaf(h0, h0*0.5f, fmaf(h1, h1*0.5f, 1e-6f)));
            float hn0 = h0 * inv, hn1 = h1 * inv;
            float g0 = hn0 * ga + hn1 * gc;
            float g1 = hn0 * (ga - gc * 1e-3f) + hn1 * gc;
            float sg0 = __builtin_amdgcn_rcpf(1.f + __builtin_amdgcn_exp2f(-g0 * LOG2E));
            float sg1 = __builtin_amdgcn_rcpf(1.f + __builtin_amdgcn_exp2f(-g1 * LOG2E));
            float y1 = cw * (g1 * sg1 - g0 * sg0) * hn0;
            outp[i] = make_float2(h0, h1 + y1);
        }
    }
}

extern "C" void kernel_launch(void* const* d_in, const int* in_sizes, int n_in,
                              void* d_out, int out_size, void* d_ws, size_t ws_size,
                              hipStream_t stream)
{
    const float* x  = (const float*)d_in[0];
    // d_in[1] = mask — causality handled analytically, unused
    const float* qw = (const float*)d_in[2];
    const float* vw = (const float*)d_in[3];
    const float* gw = (const float*)d_in[4];
    const float* cw = (const float*)d_in[5];
    float* out = (float*)d_out;

    const double omega = 2.0 * M_PI / 19.0;
    const double amp   = log(10.0) / (cos(omega * 0.3) - cos(omega * 0.7));
    const double qkns2 = amp / sqrt(2.0);               // QK_NORM_SCALE^2
    const double scale = pow(2.0, -0.5) * qkns2;        // HEAD_DIM^-0.5 * QK_NORM_SCALE^2
    const double L2E   = 1.4426950408889634074;
    const double d1    = 256.0 * omega;
    const double d2    = 512.0 * omega;

    attn_rows_kernel<<<dim3(4 * 257), dim3(256), 0, stream>>>(
        x, qw, vw, gw, cw, out,
        (float)(scale * L2E),
        (float)cos(d1),          (float)sin(d1),
        (float)cos(d2),          (float)sin(d2),
        (float)cos(omega),       (float)sin(omega),
        (float)cos(2.0 * omega), (float)sin(2.0 * omega),
        (float)cos(3.0 * omega), (float)sin(3.0 * omega));
}